// Round 1
// baseline (696.849 us; speedup 1.0000x reference)
//
#include <hip/hip_runtime.h>
#include <hip/hip_bf16.h>

// y[b,i] = sum_j x[b,j] * r[(j-i) mod N] + bias[i]
// GEMM: A = x (MxK), B[k][i] = r[(k-i) & (N-1)]  (built on the fly from r)

typedef __attribute__((ext_vector_type(8))) short bf16x8;
typedef __attribute__((ext_vector_type(4))) float f32x4;
typedef __attribute__((ext_vector_type(4))) unsigned short us4;

#define BM 128
#define BN 128
#define BK 64
#define LDP 72  // padded LDS row stride in bf16 elems (144B = 36 dwords -> conflict-free)

__device__ __forceinline__ unsigned short f2bf(float f) {
  __hip_bfloat16 h = __float2bfloat16(f);
  union { __hip_bfloat16 h; unsigned short u; } v;
  v.h = h;
  return v.u;
}

__global__ __launch_bounds__(256) void circ_gemm(
    const float* __restrict__ x, const float* __restrict__ r,
    const float* __restrict__ bias, float* __restrict__ y,
    int n) {
  __shared__ unsigned short As[BM][LDP];
  __shared__ unsigned short Bs[BN][LDP];

  const int tid = threadIdx.x;
  const int wid = tid >> 6;
  const int lane = tid & 63;
  const int bm0 = blockIdx.y * BM;
  const int bn0 = blockIdx.x * BN;
  const int m0w = (wid >> 1) * 64;   // wave's row offset in tile
  const int n0w = (wid & 1) * 64;    // wave's col offset in tile
  const int lr = lane & 15;          // frag row (A) / col (B,C)
  const int lk = (lane >> 4) * 8;    // frag k offset
  const int mask = n - 1;

  f32x4 acc[4][4];
#pragma unroll
  for (int i = 0; i < 4; ++i)
#pragma unroll
    for (int j = 0; j < 4; ++j)
      acc[i][j] = (f32x4){0.f, 0.f, 0.f, 0.f};

  const int arow = tid >> 4;        // 0..15
  const int acol = (tid & 15) * 4;  // 0..60 (float4 col)
  const int bnn = tid >> 1;         // 0..127 (B tile col index)
  const int bk0 = (tid & 1) * 32;   // k half

  for (int k0 = 0; k0 < n; k0 += BK) {
    // ---- stage A: fp32 -> bf16, 8 rows of 16 per pass ----
#pragma unroll
    for (int p = 0; p < 8; ++p) {
      const float4 v =
          *(const float4*)&x[(size_t)(bm0 + arow + p * 16) * n + k0 + acol];
      us4 h;
      h.x = f2bf(v.x); h.y = f2bf(v.y); h.z = f2bf(v.z); h.w = f2bf(v.w);
      *(us4*)&As[arow + p * 16][acol] = h;
    }
    // ---- stage B: Bs[nn][k] = bf16(r[(k0 + k - bn0 - nn) & mask]) ----
    {
      const int base = k0 + bk0 - bn0 - bnn;
#pragma unroll
      for (int kq = 0; kq < 32; kq += 4) {
        us4 h;
        h.x = f2bf(r[(base + kq + 0) & mask]);
        h.y = f2bf(r[(base + kq + 1) & mask]);
        h.z = f2bf(r[(base + kq + 2) & mask]);
        h.w = f2bf(r[(base + kq + 3) & mask]);
        *(us4*)&Bs[bnn][bk0 + kq] = h;
      }
    }
    __syncthreads();

#pragma unroll
    for (int kk = 0; kk < 2; ++kk) {
      bf16x8 af[4], bfr[4];
#pragma unroll
      for (int mi = 0; mi < 4; ++mi)
        af[mi] = *(const bf16x8*)&As[m0w + mi * 16 + lr][kk * 32 + lk];
#pragma unroll
      for (int ni = 0; ni < 4; ++ni)
        bfr[ni] = *(const bf16x8*)&Bs[n0w + ni * 16 + lr][kk * 32 + lk];
#pragma unroll
      for (int mi = 0; mi < 4; ++mi)
#pragma unroll
        for (int ni = 0; ni < 4; ++ni)
          acc[mi][ni] = __builtin_amdgcn_mfma_f32_16x16x32_bf16(
              af[mi], bfr[ni], acc[mi][ni], 0, 0, 0);
    }
    __syncthreads();
  }

  // ---- epilogue: C/D layout col=lane&15, row=(lane>>4)*4+reg ----
#pragma unroll
  for (int ni = 0; ni < 4; ++ni) {
    const int col = bn0 + n0w + ni * 16 + lr;
    const float bv = bias[col];
#pragma unroll
    for (int mi = 0; mi < 4; ++mi) {
      const int row0 = bm0 + m0w + mi * 16 + (lane >> 4) * 4;
#pragma unroll
      for (int j = 0; j < 4; ++j)
        y[(size_t)(row0 + j) * n + col] = acc[mi][ni][j] + bv;
    }
  }
}

extern "C" void kernel_launch(void* const* d_in, const int* in_sizes, int n_in,
                              void* d_out, int out_size, void* d_ws,
                              size_t ws_size, hipStream_t stream) {
  const float* x = (const float*)d_in[0];
  const float* r = (const float*)d_in[1];
  const float* b = (const float*)d_in[2];
  float* y = (float*)d_out;
  const int n = in_sizes[1];            // 4096
  const int batch = in_sizes[0] / n;    // 8192
  dim3 grid(n / BN, batch / BM);
  circ_gemm<<<grid, dim3(256, 1, 1), 0, stream>>>(x, r, b, y, n);
}

// Round 2
// 385.421 us; speedup vs baseline: 1.8080x; 1.8080x over previous
//
#include <hip/hip_runtime.h>
#include <hip/hip_bf16.h>

// y[b,i] = sum_j x[b,j] * r[(j-i) mod N] + bias[i]
// Fast path: xb = bf16(x) in ws; Bt[i][k] = bf16(r[(k-i)&mask]) in ws;
//            m97-structure GEMM (global_load_lds + swizzled LDS).

typedef __attribute__((ext_vector_type(8))) short bf16x8;
typedef __attribute__((ext_vector_type(4))) float f32x4;
typedef __attribute__((ext_vector_type(8))) unsigned short us8;
typedef __attribute__((ext_vector_type(4))) unsigned short us4;

__device__ __forceinline__ unsigned short f2bf(float f) {
  union { __hip_bfloat16 h; unsigned short u; } v;
  v.h = __float2bfloat16(f);
  return v.u;
}

__device__ __forceinline__ void gload_lds16(const void* g, void* l) {
  __builtin_amdgcn_global_load_lds(
      (const __attribute__((address_space(1))) void*)g,
      (__attribute__((address_space(3))) void*)l, 16, 0, 0);
}

// ---------------- converters ----------------

__global__ __launch_bounds__(256) void conv_x_kernel(
    const float* __restrict__ x, unsigned short* __restrict__ xb,
    size_t total8) {
  size_t i = (size_t)blockIdx.x * blockDim.x + threadIdx.x;
  const size_t stride = (size_t)gridDim.x * blockDim.x;
  for (; i < total8; i += stride) {
    const float4 v0 = ((const float4*)x)[2 * i];
    const float4 v1 = ((const float4*)x)[2 * i + 1];
    us8 o;
    o[0] = f2bf(v0.x); o[1] = f2bf(v0.y); o[2] = f2bf(v0.z); o[3] = f2bf(v0.w);
    o[4] = f2bf(v1.x); o[5] = f2bf(v1.y); o[6] = f2bf(v1.z); o[7] = f2bf(v1.w);
    ((us8*)xb)[i] = o;
  }
}

__global__ __launch_bounds__(256) void build_bt_kernel(
    const float* __restrict__ r, unsigned short* __restrict__ bt, int n,
    int logn) {
  const int mask = n - 1;
  const size_t total8 = ((size_t)n * n) >> 3;
  size_t i = (size_t)blockIdx.x * blockDim.x + threadIdx.x;
  const size_t stride = (size_t)gridDim.x * blockDim.x;
  for (; i < total8; i += stride) {
    const size_t e0 = i << 3;
    const int row = (int)(e0 >> logn);
    const int k0 = (int)(e0 & (size_t)mask);
    const int base = k0 - row;
    us8 o;
#pragma unroll
    for (int t = 0; t < 8; ++t) o[t] = f2bf(r[(base + t) & mask]);
    ((us8*)bt)[i] = o;
  }
}

// ---------------- m97-structure GEMM ----------------

#define TM 128
#define TN 128
#define TK 64

__global__ __launch_bounds__(256) void circ_gemm2(
    const unsigned short* __restrict__ A, const unsigned short* __restrict__ B,
    const float* __restrict__ bias, float* __restrict__ y, int n, int nbn) {
  __shared__ unsigned short As[TM * TK];  // swizzled [row][chunk^(row&7)]
  __shared__ unsigned short Bs[TN * TK];

  // XCD-aware swizzle (nwg % 8 == 0 guaranteed: 2048 blocks)
  const int nwg = gridDim.x;
  const int cpx = nwg >> 3;
  const int b0 = blockIdx.x;
  const int wg = (b0 & 7) * cpx + (b0 >> 3);
  const int bn0 = (wg & (nbn - 1)) * TN;
  const int bm0 = (wg / nbn) * TM;

  const int tid = threadIdx.x;
  const int wid = tid >> 6;
  const int lane = tid & 63;
  const int lr = lane & 15;
  const int g = lane >> 4;
  const int h = lr & 7;
  const int m0w = (wid >> 1) * 64;
  const int n0w = (wid & 1) * 64;

  // staging: instruction j covers tile rows 8j..8j+7; lane l -> row 8j+(l>>3),
  // stored chunk (l&7); pre-swizzled source chunk = (l&7)^(l>>3)
  const int srow = lane >> 3;
  const int schunk = (lane & 7) ^ srow;
  size_t aoff[4], boff[4];
  int ldsoff[4];
#pragma unroll
  for (int i = 0; i < 4; ++i) {
    const int j = wid * 4 + i;
    aoff[i] = (size_t)(bm0 + 8 * j + srow) * n + schunk * 8;
    boff[i] = (size_t)(bn0 + 8 * j + srow) * n + schunk * 8;
    ldsoff[i] = j * 512;  // elements; 1024 B per instruction
  }

  f32x4 acc[4][4];
#pragma unroll
  for (int i = 0; i < 4; ++i)
#pragma unroll
    for (int j = 0; j < 4; ++j) acc[i][j] = (f32x4){0.f, 0.f, 0.f, 0.f};

  for (int k0 = 0; k0 < n; k0 += TK) {
#pragma unroll
    for (int i = 0; i < 4; ++i)
      gload_lds16(A + aoff[i] + k0, (void*)(As + ldsoff[i]));
#pragma unroll
    for (int i = 0; i < 4; ++i)
      gload_lds16(B + boff[i] + k0, (void*)(Bs + ldsoff[i]));
    __syncthreads();  // drains vmcnt(0) before barrier

#pragma unroll
    for (int kk = 0; kk < 2; ++kk) {
      bf16x8 af[4], bfv[4];
      const int c = ((kk * 4 + g) ^ h) << 3;  // swizzled chunk offset (elems)
#pragma unroll
      for (int mi = 0; mi < 4; ++mi)
        af[mi] = *(const bf16x8*)&As[(m0w + mi * 16 + lr) * TK + c];
#pragma unroll
      for (int ni = 0; ni < 4; ++ni)
        bfv[ni] = *(const bf16x8*)&Bs[(n0w + ni * 16 + lr) * TK + c];
#pragma unroll
      for (int mi = 0; mi < 4; ++mi)
#pragma unroll
        for (int ni = 0; ni < 4; ++ni)
          acc[mi][ni] = __builtin_amdgcn_mfma_f32_16x16x32_bf16(
              af[mi], bfv[ni], acc[mi][ni], 0, 0, 0);
    }
    __syncthreads();
  }

  // epilogue: C/D layout col=lane&15, row=(lane>>4)*4+reg
#pragma unroll
  for (int ni = 0; ni < 4; ++ni) {
    const int col = bn0 + n0w + ni * 16 + lr;
    const float bv = bias[col];
#pragma unroll
    for (int mi = 0; mi < 4; ++mi) {
      const int row0 = bm0 + m0w + mi * 16 + g * 4;
#pragma unroll
      for (int j = 0; j < 4; ++j)
        y[(size_t)(row0 + j) * n + col] = acc[mi][ni][j] + bv;
    }
  }
}

// ---------------- fallback (round-1 kernel, no ws needed) ----------------

#define LDP 72

__global__ __launch_bounds__(256) void circ_gemm_fb(
    const float* __restrict__ x, const float* __restrict__ r,
    const float* __restrict__ bias, float* __restrict__ y, int n) {
  __shared__ unsigned short As[128][LDP];
  __shared__ unsigned short Bs[128][LDP];

  const int tid = threadIdx.x;
  const int wid = tid >> 6;
  const int lane = tid & 63;
  const int bm0 = blockIdx.y * 128;
  const int bn0 = blockIdx.x * 128;
  const int m0w = (wid >> 1) * 64;
  const int n0w = (wid & 1) * 64;
  const int lr = lane & 15;
  const int lk = (lane >> 4) * 8;
  const int mask = n - 1;

  f32x4 acc[4][4];
#pragma unroll
  for (int i = 0; i < 4; ++i)
#pragma unroll
    for (int j = 0; j < 4; ++j) acc[i][j] = (f32x4){0.f, 0.f, 0.f, 0.f};

  const int arow = tid >> 4;
  const int acol = (tid & 15) * 4;
  const int bnn = tid >> 1;
  const int bk0 = (tid & 1) * 32;

  for (int k0 = 0; k0 < n; k0 += 64) {
#pragma unroll
    for (int p = 0; p < 8; ++p) {
      const float4 v =
          *(const float4*)&x[(size_t)(bm0 + arow + p * 16) * n + k0 + acol];
      us4 hh;
      hh.x = f2bf(v.x); hh.y = f2bf(v.y); hh.z = f2bf(v.z); hh.w = f2bf(v.w);
      *(us4*)&As[arow + p * 16][acol] = hh;
    }
    {
      const int base = k0 + bk0 - bn0 - bnn;
#pragma unroll
      for (int kq = 0; kq < 32; kq += 4) {
        us4 hh;
        hh.x = f2bf(r[(base + kq + 0) & mask]);
        hh.y = f2bf(r[(base + kq + 1) & mask]);
        hh.z = f2bf(r[(base + kq + 2) & mask]);
        hh.w = f2bf(r[(base + kq + 3) & mask]);
        *(us4*)&Bs[bnn][bk0 + kq] = hh;
      }
    }
    __syncthreads();

#pragma unroll
    for (int kk = 0; kk < 2; ++kk) {
      bf16x8 af[4], bfr[4];
#pragma unroll
      for (int mi = 0; mi < 4; ++mi)
        af[mi] = *(const bf16x8*)&As[m0w + mi * 16 + lr][kk * 32 + lk];
#pragma unroll
      for (int ni = 0; ni < 4; ++ni)
        bfr[ni] = *(const bf16x8*)&Bs[n0w + ni * 16 + lr][kk * 32 + lk];
#pragma unroll
      for (int mi = 0; mi < 4; ++mi)
#pragma unroll
        for (int ni = 0; ni < 4; ++ni)
          acc[mi][ni] = __builtin_amdgcn_mfma_f32_16x16x32_bf16(
              af[mi], bfr[ni], acc[mi][ni], 0, 0, 0);
    }
    __syncthreads();
  }

#pragma unroll
  for (int ni = 0; ni < 4; ++ni) {
    const int col = bn0 + n0w + ni * 16 + lr;
    const float bv = bias[col];
#pragma unroll
    for (int mi = 0; mi < 4; ++mi) {
      const int row0 = bm0 + m0w + mi * 16 + (lane >> 4) * 4;
#pragma unroll
      for (int j = 0; j < 4; ++j)
        y[(size_t)(row0 + j) * n + col] = acc[mi][ni][j] + bv;
    }
  }
}

// ---------------- launch ----------------

extern "C" void kernel_launch(void* const* d_in, const int* in_sizes, int n_in,
                              void* d_out, int out_size, void* d_ws,
                              size_t ws_size, hipStream_t stream) {
  const float* x = (const float*)d_in[0];
  const float* r = (const float*)d_in[1];
  const float* b = (const float*)d_in[2];
  float* y = (float*)d_out;
  const int n = in_sizes[1];          // 4096
  const int batch = in_sizes[0] / n;  // 8192

  const size_t xb_elems = (size_t)batch * n;
  const size_t bt_elems = (size_t)n * n;
  const size_t need = (xb_elems + bt_elems) * sizeof(unsigned short);

  if (ws_size >= need) {
    unsigned short* xb = (unsigned short*)d_ws;
    unsigned short* bt = xb + xb_elems;
    int logn = 31 - __builtin_clz((unsigned)n);
    conv_x_kernel<<<2048, 256, 0, stream>>>(x, xb, xb_elems / 8);
    build_bt_kernel<<<1024, 256, 0, stream>>>(r, bt, n, logn);
    dim3 grid((batch / TM) * (n / TN));
    circ_gemm2<<<grid, 256, 0, stream>>>(xb, bt, b, y, n, n / TN);
  } else {
    dim3 grid(n / 128, batch / 128);
    circ_gemm_fb<<<grid, 256, 0, stream>>>(x, r, b, y, n);
  }
}

// Round 3
// 322.432 us; speedup vs baseline: 2.1612x; 1.1954x over previous
//
#include <hip/hip_runtime.h>
#include <hip/hip_bf16.h>

// y[b,i] = sum_j x[b,j] * r[(j-i) mod N] + bias[i]
// Fast path: xb = bf16(x), Bt[i][k] = bf16(r[(k-i)&mask]) in ws;
//            256x256 8-phase GEMM (T1+T2+T3+T4+T5 stack).

typedef __attribute__((ext_vector_type(8))) short bf16x8;
typedef __attribute__((ext_vector_type(4))) float f32x4;
typedef __attribute__((ext_vector_type(8))) unsigned short us8;
typedef __attribute__((ext_vector_type(4))) unsigned short us4;

__device__ __forceinline__ unsigned short f2bf(float f) {
  union { __hip_bfloat16 h; unsigned short u; } v;
  v.h = __float2bfloat16(f);
  return v.u;
}

__device__ __forceinline__ void gload_lds16(const void* g, void* l) {
  __builtin_amdgcn_global_load_lds(
      (const __attribute__((address_space(1))) void*)g,
      (__attribute__((address_space(3))) void*)l, 16, 0, 0);
}

#define SBAR() __builtin_amdgcn_s_barrier()
#define SCHED0() __builtin_amdgcn_sched_barrier(0)
#define LGKM0() asm volatile("s_waitcnt lgkmcnt(0)" ::: "memory")
#define VM0() asm volatile("s_waitcnt vmcnt(0)" ::: "memory")

// ---------------- converters ----------------

__global__ __launch_bounds__(256) void conv_x_kernel(
    const float* __restrict__ x, unsigned short* __restrict__ xb,
    size_t total8) {
  size_t i = (size_t)blockIdx.x * blockDim.x + threadIdx.x;
  const size_t stride = (size_t)gridDim.x * blockDim.x;
  for (; i < total8; i += stride) {
    const float4 v0 = ((const float4*)x)[2 * i];
    const float4 v1 = ((const float4*)x)[2 * i + 1];
    us8 o;
    o[0] = f2bf(v0.x); o[1] = f2bf(v0.y); o[2] = f2bf(v0.z); o[3] = f2bf(v0.w);
    o[4] = f2bf(v1.x); o[5] = f2bf(v1.y); o[6] = f2bf(v1.z); o[7] = f2bf(v1.w);
    ((us8*)xb)[i] = o;
  }
}

__global__ __launch_bounds__(256) void build_bt_kernel(
    const float* __restrict__ r, unsigned short* __restrict__ bt, int n,
    int logn) {
  const int mask = n - 1;
  const size_t total8 = ((size_t)n * n) >> 3;
  size_t i = (size_t)blockIdx.x * blockDim.x + threadIdx.x;
  const size_t stride = (size_t)gridDim.x * blockDim.x;
  for (; i < total8; i += stride) {
    const size_t e0 = i << 3;
    const int row = (int)(e0 >> logn);
    const int k0 = (int)(e0 & (size_t)mask);
    const int base = k0 - row;
    us8 o;
#pragma unroll
    for (int t = 0; t < 8; ++t) o[t] = f2bf(r[(base + t) & mask]);
    ((us8*)bt)[i] = o;
  }
}

// ---------------- 256x256 8-phase GEMM ----------------
// 8 waves (2M x 4N); per-wave C = 128x64 = acc[8][4] 16x16 frags.
// LDS: double-buffered 256x64 bf16 tiles for A and B (128 KiB).
// XOR swizzle: phys_chunk = logical_chunk ^ (row & 7) (16B chunks) -> 0 conflicts.

__global__ __launch_bounds__(512, 2) void circ_gemm3(
    const unsigned short* __restrict__ A, const unsigned short* __restrict__ B,
    const float* __restrict__ bias, float* __restrict__ y, int n, int nbn) {
  __shared__ unsigned short As[2 * 256 * 64];
  __shared__ unsigned short Bs[2 * 256 * 64];

  // XCD-aware swizzle (nwg % 8 == 0: 512 blocks)
  const int nwg = gridDim.x;
  const int cpx = nwg >> 3;
  const int b0 = blockIdx.x;
  const int wg = (b0 & 7) * cpx + (b0 >> 3);
  const int bn0 = (wg % nbn) * 256;
  const int bm0 = (wg / nbn) * 256;

  const int tid = threadIdx.x;
  const int wid = tid >> 6;
  const int lane = tid & 63;
  const int wm = wid >> 2;   // 0..1
  const int wn = wid & 3;    // 0..3
  const int lr = lane & 15;
  const int g = lane >> 4;   // 0..3
  const int hx = lr & 7;

  // staging: wave wid issues instructions j = wid*4+i; inst j covers tile
  // rows 8j..8j+7; lane l -> row 8j+(l>>3), phys chunk (l&7);
  // pre-swizzled source chunk = (l&7)^(l>>3)
  const int srow = lane >> 3;
  const int schunk = (lane & 7) ^ srow;
  unsigned aoff[4], boff[4];
  int ldso[4];
#pragma unroll
  for (int i = 0; i < 4; ++i) {
    const int j = wid * 4 + i;
    aoff[i] = (unsigned)(bm0 + 8 * j + srow) * (unsigned)n + schunk * 8;
    boff[i] = (unsigned)(bn0 + 8 * j + srow) * (unsigned)n + schunk * 8;
    ldso[i] = j * 512;  // elements (1024 B per instruction)
  }

  f32x4 acc[8][4];
#pragma unroll
  for (int i = 0; i < 8; ++i)
#pragma unroll
    for (int j = 0; j < 4; ++j) acc[i][j] = (f32x4){0.f, 0.f, 0.f, 0.f};

  const int aRow = wm * 128 + lr;  // + mi*16
  const int bRow = wn * 64 + lr;   // + ni*16
  const int c0 = ((0 + g) ^ hx) << 3;  // kk0 swizzled chunk, elem offset
  const int c1 = ((4 + g) ^ hx) << 3;  // kk1

  const int nt = n >> 6;

  // ---- prologue: stage tile 0 into buf 0, drain ----
#pragma unroll
  for (int i = 0; i < 4; ++i) gload_lds16(A + aoff[i], As + ldso[i]);
#pragma unroll
  for (int i = 0; i < 4; ++i) gload_lds16(B + boff[i], Bs + ldso[i]);
  VM0();
  SCHED0();
  SBAR();
  SCHED0();

  for (int t = 0; t < nt; ++t) {
    const int cb = (t & 1) << 14;          // current buf elem offset (16384)
    const int nb = ((t & 1) ^ 1) << 14;    // next buf
    const unsigned short* Ac = As + cb;
    const unsigned short* Bc = Bs + cb;
    const unsigned kof = (unsigned)(t + 1) << 6;
    const bool pf = (t + 1) < nt;

    bf16x8 a0[4], a1[4], bf[4];

    // ===== phase 0: read A(mi 0-3, kk0) + B(ni 0-3, kk0); stage next A =====
#pragma unroll
    for (int mi = 0; mi < 4; ++mi)
      a0[mi] = *(const bf16x8*)&Ac[(aRow + mi * 16) * 64 + c0];
#pragma unroll
    for (int ni = 0; ni < 4; ++ni)
      bf[ni] = *(const bf16x8*)&Bc[(bRow + ni * 16) * 64 + c0];
    if (pf) {
#pragma unroll
      for (int i = 0; i < 4; ++i)
        gload_lds16(A + (aoff[i] + kof), As + (nb + ldso[i]));
    }
    SCHED0(); SBAR(); LGKM0(); SCHED0();
    __builtin_amdgcn_s_setprio(1);
#pragma unroll
    for (int mi = 0; mi < 4; ++mi)
#pragma unroll
      for (int ni = 0; ni < 4; ++ni)
        acc[mi][ni] = __builtin_amdgcn_mfma_f32_16x16x32_bf16(
            a0[mi], bf[ni], acc[mi][ni], 0, 0, 0);
    __builtin_amdgcn_s_setprio(0);
    SCHED0(); SBAR(); SCHED0();

    // ===== phase 1: read A(mi 4-7, kk0); stage next B =====
#pragma unroll
    for (int mi = 0; mi < 4; ++mi)
      a1[mi] = *(const bf16x8*)&Ac[(aRow + 64 + mi * 16) * 64 + c0];
    if (pf) {
#pragma unroll
      for (int i = 0; i < 4; ++i)
        gload_lds16(B + (boff[i] + kof), Bs + (nb + ldso[i]));
    }
    SCHED0(); SBAR(); LGKM0(); SCHED0();
    __builtin_amdgcn_s_setprio(1);
#pragma unroll
    for (int mi = 0; mi < 4; ++mi)
#pragma unroll
      for (int ni = 0; ni < 4; ++ni)
        acc[4 + mi][ni] = __builtin_amdgcn_mfma_f32_16x16x32_bf16(
            a1[mi], bf[ni], acc[4 + mi][ni], 0, 0, 0);
    __builtin_amdgcn_s_setprio(0);
    SCHED0(); SBAR(); SCHED0();

    // ===== phase 2: read A(mi 0-3, kk1) + B(ni 0-3, kk1) =====
#pragma unroll
    for (int mi = 0; mi < 4; ++mi)
      a0[mi] = *(const bf16x8*)&Ac[(aRow + mi * 16) * 64 + c1];
#pragma unroll
    for (int ni = 0; ni < 4; ++ni)
      bf[ni] = *(const bf16x8*)&Bc[(bRow + ni * 16) * 64 + c1];
    SCHED0(); SBAR(); LGKM0(); SCHED0();
    __builtin_amdgcn_s_setprio(1);
#pragma unroll
    for (int mi = 0; mi < 4; ++mi)
#pragma unroll
      for (int ni = 0; ni < 4; ++ni)
        acc[mi][ni] = __builtin_amdgcn_mfma_f32_16x16x32_bf16(
            a0[mi], bf[ni], acc[mi][ni], 0, 0, 0);
    __builtin_amdgcn_s_setprio(0);
    SCHED0(); SBAR(); SCHED0();

    // ===== phase 3: read A(mi 4-7, kk1); drain stages; tile boundary =====
#pragma unroll
    for (int mi = 0; mi < 4; ++mi)
      a1[mi] = *(const bf16x8*)&Ac[(aRow + 64 + mi * 16) * 64 + c1];
    SCHED0(); SBAR(); LGKM0(); SCHED0();
    __builtin_amdgcn_s_setprio(1);
#pragma unroll
    for (int mi = 0; mi < 4; ++mi)
#pragma unroll
      for (int ni = 0; ni < 4; ++ni)
        acc[4 + mi][ni] = __builtin_amdgcn_mfma_f32_16x16x32_bf16(
            a1[mi], bf[ni], acc[4 + mi][ni], 0, 0, 0);
    __builtin_amdgcn_s_setprio(0);
    if (pf) { VM0(); }
    SCHED0(); SBAR(); SCHED0();
  }

  // ---- epilogue: C/D layout col=lane&15, row=(lane>>4)*4+reg ----
#pragma unroll
  for (int ni = 0; ni < 4; ++ni) {
    const int col = bn0 + wn * 64 + ni * 16 + lr;
    const float bv = bias[col];
#pragma unroll
    for (int mi = 0; mi < 8; ++mi) {
      const int row0 = bm0 + wm * 128 + mi * 16 + g * 4;
#pragma unroll
      for (int j = 0; j < 4; ++j)
        y[(size_t)(row0 + j) * n + col] = acc[mi][ni][j] + bv;
    }
  }
}

// ---------------- fallback (no ws needed) ----------------

#define LDP 72

__global__ __launch_bounds__(256) void circ_gemm_fb(
    const float* __restrict__ x, const float* __restrict__ r,
    const float* __restrict__ bias, float* __restrict__ y, int n) {
  __shared__ unsigned short Asf[128][LDP];
  __shared__ unsigned short Bsf[128][LDP];

  const int tid = threadIdx.x;
  const int wid = tid >> 6;
  const int lane = tid & 63;
  const int bm0 = blockIdx.y * 128;
  const int bn0 = blockIdx.x * 128;
  const int m0w = (wid >> 1) * 64;
  const int n0w = (wid & 1) * 64;
  const int lr = lane & 15;
  const int lk = (lane >> 4) * 8;
  const int mask = n - 1;

  f32x4 acc[4][4];
#pragma unroll
  for (int i = 0; i < 4; ++i)
#pragma unroll
    for (int j = 0; j < 4; ++j) acc[i][j] = (f32x4){0.f, 0.f, 0.f, 0.f};

  const int arow = tid >> 4;
  const int acol = (tid & 15) * 4;
  const int bnn = tid >> 1;
  const int bk0 = (tid & 1) * 32;

  for (int k0 = 0; k0 < n; k0 += 64) {
#pragma unroll
    for (int p = 0; p < 8; ++p) {
      const float4 v =
          *(const float4*)&x[(size_t)(bm0 + arow + p * 16) * n + k0 + acol];
      us4 hh;
      hh.x = f2bf(v.x); hh.y = f2bf(v.y); hh.z = f2bf(v.z); hh.w = f2bf(v.w);
      *(us4*)&Asf[arow + p * 16][acol] = hh;
    }
    {
      const int base = k0 + bk0 - bn0 - bnn;
#pragma unroll
      for (int kq = 0; kq < 32; kq += 4) {
        us4 hh;
        hh.x = f2bf(r[(base + kq + 0) & mask]);
        hh.y = f2bf(r[(base + kq + 1) & mask]);
        hh.z = f2bf(r[(base + kq + 2) & mask]);
        hh.w = f2bf(r[(base + kq + 3) & mask]);
        *(us4*)&Bsf[bnn][bk0 + kq] = hh;
      }
    }
    __syncthreads();

#pragma unroll
    for (int kk = 0; kk < 2; ++kk) {
      bf16x8 af[4], bfr[4];
#pragma unroll
      for (int mi = 0; mi < 4; ++mi)
        af[mi] = *(const bf16x8*)&Asf[m0w + mi * 16 + lr][kk * 32 + lk];
#pragma unroll
      for (int ni = 0; ni < 4; ++ni)
        bfr[ni] = *(const bf16x8*)&Bsf[n0w + ni * 16 + lr][kk * 32 + lk];
#pragma unroll
      for (int mi = 0; mi < 4; ++mi)
#pragma unroll
        for (int ni = 0; ni < 4; ++ni)
          acc[mi][ni] = __builtin_amdgcn_mfma_f32_16x16x32_bf16(
              af[mi], bfr[ni], acc[mi][ni], 0, 0, 0);
    }
    __syncthreads();
  }

#pragma unroll
  for (int ni = 0; ni < 4; ++ni) {
    const int col = bn0 + n0w + ni * 16 + lr;
    const float bv = bias[col];
#pragma unroll
    for (int mi = 0; mi < 4; ++mi) {
      const int row0 = bm0 + m0w + mi * 16 + (lane >> 4) * 4;
#pragma unroll
      for (int j = 0; j < 4; ++j)
        y[(size_t)(row0 + j) * n + col] = acc[mi][ni][j] + bv;
    }
  }
}

// ---------------- launch ----------------

extern "C" void kernel_launch(void* const* d_in, const int* in_sizes, int n_in,
                              void* d_out, int out_size, void* d_ws,
                              size_t ws_size, hipStream_t stream) {
  const float* x = (const float*)d_in[0];
  const float* r = (const float*)d_in[1];
  const float* b = (const float*)d_in[2];
  float* y = (float*)d_out;
  const int n = in_sizes[1];          // 4096
  const int batch = in_sizes[0] / n;  // 8192

  const size_t xb_elems = (size_t)batch * n;
  const size_t bt_elems = (size_t)n * n;
  const size_t need = (xb_elems + bt_elems) * sizeof(unsigned short);

  if (ws_size >= need && (n % 256) == 0 && (batch % 256) == 0) {
    unsigned short* xb = (unsigned short*)d_ws;
    unsigned short* bt = xb + xb_elems;
    int logn = 31 - __builtin_clz((unsigned)n);
    conv_x_kernel<<<2048, 256, 0, stream>>>(x, xb, xb_elems / 8);
    build_bt_kernel<<<1024, 256, 0, stream>>>(r, bt, n, logn);
    dim3 grid((batch / 256) * (n / 256));
    circ_gemm3<<<grid, 512, 0, stream>>>(xb, bt, b, y, n, n / 256);
  } else {
    dim3 grid(n / 128, batch / 128);
    circ_gemm_fb<<<grid, 256, 0, stream>>>(x, r, b, y, n);
  }
}